// Round 23
// baseline (174.698 us; speedup 1.0000x reference)
//
#include <hip/hip_runtime.h>
#include <math.h>

#define B_ 16
#define H_ 10
#define L_ 4096
#define S_ 77
#define D_ 64
#define NE_ 20
#define NP_ (B_*NE_)
#define NBLK_ ((L_/128)*B_)   // k1 grid size = 512
#define SHRINK_ 2.0f
#define LOG2E 1.4426950408889634f
#define SC_L2 (0.125f*LOG2E)
#define IT_ 8   // k3 l-tiles per block; 8 waves x 16 rows x IT_ = 1024 rows/block -> grid 640

typedef __bf16 bf16x8 __attribute__((ext_vector_type(8)));
typedef float  f32x4  __attribute__((ext_vector_type(4)));

static __device__ __forceinline__ unsigned short bfb(__bf16 x) {
  return __builtin_bit_cast(unsigned short, x);
}
static __device__ __forceinline__ __bf16 mkbf(unsigned short x) {
  return __builtin_bit_cast(__bf16, x);
}

// ---------------- K1: subj scores via MFMA + moment accumulation + LAST-BLOCK FINISH ----
// Moment path unchanged from R20/R22 (atomics + memset; R21's partials regressed).
// NEW (round 23): the last k1 block to finish (device counter) executes the
// ex-k2b work once -- params from moments, global grid-max, pmap scatter --
// saving the k2b dispatch + one inter-kernel gap. __threadfence() before the
// counter increment makes all blocks' moment atomics visible; the finisher
// reads moments with volatile (L1-bypassing) loads.
__global__ __launch_bounds__(256, 3) void k1_subj(const float* __restrict__ Q,
                                                  const float* __restrict__ K,
                                                  const int* __restrict__ idxb,
                                                  const int* __restrict__ idxn,
                                                  float* __restrict__ moments,
                                                  int* __restrict__ counter,
                                                  float* __restrict__ params,
                                                  int* __restrict__ pmap,
                                                  float* __restrict__ l2invg) {
  __shared__ __bf16 KF[20][2][64][8];   // 40 KB
  __shared__ float T[NE_][66];          // transpose tile (pair x 64 l)
  __shared__ float redf[4];
  __shared__ int bs[NE_], ss[NE_], s_uni, lastf;
  const int i = blockIdx.y, bx = blockIdx.x;
  const int tid = threadIdx.x, lane = tid & 63, wid = tid >> 6;
  const int c = lane & 15, g = lane >> 4;
  if (tid < NE_) { bs[tid] = idxb[i*NE_ + tid]; ss[tid] = idxn[i*NE_ + tid]; }
  __syncthreads();
  if (tid == 0) { int u = 1; for (int j = 1; j < NE_; ++j) u &= (bs[j] == bs[0]); s_uni = u; }
  for (int e4 = tid; e4 < 32*160; e4 += 256) {
    int j = e4 / 160, k = (e4 - j*160) * 4;
    float4 kv = make_float4(0.f, 0.f, 0.f, 0.f);
    if (j < NE_) kv = *(const float4*)&K[(((size_t)bs[j]*H_ + (k >> 6))*S_ + ss[j])*D_ + (k & 63)];
    int ks = k >> 5, gg = (k >> 3) & 3, jj = k & 7, n = j >> 4, cc = j & 15;
    uint2 pk;
    pk.x = (unsigned)bfb((__bf16)kv.x) | ((unsigned)bfb((__bf16)kv.y) << 16);
    pk.y = (unsigned)bfb((__bf16)kv.z) | ((unsigned)bfb((__bf16)kv.w) << 16);
    *(uint2*)&KF[ks][n][gg*16 + cc][jj] = pk;
  }
  __syncthreads();
  if (!s_uni) {
    // generic fallback (idx_b varies within a row): correctness-only
    int ll = tid & 63;
    for (int ii = 0; ii < 2; ++ii) {
      int l = bx*128 + ii*64 + ll;
      for (int j = tid >> 6; j < NE_; j += 4) {
        float a = 0.f;
        for (int h = 0; h < H_; ++h) {
          const float* qp = Q + (((size_t)bs[j]*H_ + h)*L_ + l)*D_;
          const float* kp = K + (((size_t)bs[j]*H_ + h)*S_ + ss[j])*D_;
          for (int d = 0; d < 64; ++d) a += qp[d]*kp[d];
        }
        float e = __builtin_amdgcn_exp2f(a * (1.0f/80.0f) * LOG2E);
        float y = (float)(l >> 6), x = (float)(l & 63);
        atomicAdd(&moments[(i*NE_ + j)*8 + 0], e);
        atomicAdd(&moments[(i*NE_ + j)*8 + 1], e*y);
        atomicAdd(&moments[(i*NE_ + j)*8 + 2], e*x);
        atomicAdd(&moments[(i*NE_ + j)*8 + 3], e*y*y);
        atomicAdd(&moments[(i*NE_ + j)*8 + 4], e*x*x);
      }
    }
  } else {
    const int b0 = bs[0];
    const int rj = tid >> 3;          // pair handled in reduce (active if < 20)
    const int rl = (tid & 7) * 8;     // 8-element slice
    float m0 = 0.f, m1 = 0.f, m2 = 0.f, m3 = 0.f, m4 = 0.f;
    #pragma unroll 1
    for (int it = 0; it < 2; ++it) {
      const int lrow = bx*128 + it*64 + wid*16 + c;
      f32x4 acc0 = {0.f,0.f,0.f,0.f}, acc1 = {0.f,0.f,0.f,0.f};
      #pragma unroll 4
      for (int ks = 0; ks < 20; ++ks) {
        const float* qp = Q + (((size_t)b0*H_ + (ks >> 1))*L_ + lrow)*D_ + (ks & 1)*32 + g*8;
        const float4 a = *(const float4*)qp;
        const float4 bq = *(const float4*)(qp + 4);
        bf16x8 af;
        af[0]=(__bf16)a.x;  af[1]=(__bf16)a.y;  af[2]=(__bf16)a.z;  af[3]=(__bf16)a.w;
        af[4]=(__bf16)bq.x; af[5]=(__bf16)bq.y; af[6]=(__bf16)bq.z; af[7]=(__bf16)bq.w;
        bf16x8 k0 = *(bf16x8*)&KF[ks][0][lane][0];
        bf16x8 k1 = *(bf16x8*)&KF[ks][1][lane][0];
        acc0 = __builtin_amdgcn_mfma_f32_16x16x32_bf16(af, k0, acc0, 0, 0, 0);
        acc1 = __builtin_amdgcn_mfma_f32_16x16x32_bf16(af, k1, acc1, 0, 0, 0);
      }
      const float sc = 1.0f/80.0f;
      #pragma unroll
      for (int r = 0; r < 4; ++r) {
        int ll = wid*16 + g*4 + r;
        T[c][ll] = acc0[r]*sc;
        if (c < 4) T[16 + c][ll] = acc1[r]*sc;
      }
      __syncthreads();
      // parallel moment reduce of this 64-l tile; y = Y0 constant over tile
      if (rj < NE_) {
        float s0 = 0.f, s1 = 0.f, s2 = 0.f;
        #pragma unroll
        for (int u = 0; u < 8; ++u) {
          float e = __builtin_amdgcn_exp2f(T[rj][rl + u] * LOG2E);
          float x = (float)(rl + u);
          s0 += e; s1 += e*x; s2 += e*x*x;
        }
        #pragma unroll
        for (int s = 1; s < 8; s <<= 1) {
          s0 += __shfl_xor(s0, s, 64);
          s1 += __shfl_xor(s1, s, 64);
          s2 += __shfl_xor(s2, s, 64);
        }
        if ((tid & 7) == 0) {
          const float Y0 = (float)(bx*2 + it);
          m0 += s0; m1 += Y0*s0; m2 += s1; m3 += Y0*Y0*s0; m4 += s2;
        }
      }
      __syncthreads();
    }
    if (rj < NE_ && (tid & 7) == 0) {
      float* mp = &moments[(size_t)(i*NE_ + rj)*8];
      atomicAdd(mp + 0, m0);
      atomicAdd(mp + 1, m1);
      atomicAdd(mp + 2, m2);
      atomicAdd(mp + 3, m3);
      atomicAdd(mp + 4, m4);
    }
  }

  // ---- last-block finish (merged ex-k2b) ----
  __threadfence();   // moment atomics visible device-wide before counter bump
  if (tid == 0) lastf = (atomicAdd(counter, 1) == NBLK_ - 1);
  __syncthreads();
  if (!lastf) return;
  // All 512 blocks' fences precede their observed increments -> moments complete.
  const volatile float* mom = moments;   // L1-bypassing reads
  float mx = 0.f;
  for (int p = tid; p < NP_; p += 256) {
    float m0 = mom[p*8+0], m1 = mom[p*8+1], m2 = mom[p*8+2];
    float m3 = mom[p*8+3], m4 = mom[p*8+4];
    float xc = m2/m0, yc = m1/m0;
    float varx = m4/m0 - xc*xc, vary = m3/m0 - yc*yc;
    float sh = SHRINK_ - 1.0f;
    float isx = sh*sh/(2.f*varx), isy = sh*sh/(2.f*vary);
    float rx = rintf(xc), ry = rintf(yc);
    float mv = __expf(-((rx-xc)*(rx-xc)*isx + (ry-yc)*(ry-yc)*isy));
    params[p*8+0] = xc; params[p*8+1] = yc;
    params[p*8+2] = isx; params[p*8+3] = isy; params[p*8+4] = mv;
    mx = fmaxf(mx, mv);
  }
  #pragma unroll
  for (int s = 1; s < 64; s <<= 1) mx = fmaxf(mx, __shfl_xor(mx, s, 64));
  if (lane == 0) redf[wid] = mx;
  for (int e = tid; e < B_*S_; e += 256) pmap[e] = -1;
  __syncthreads();
  for (int p = tid; p < NP_; p += 256) pmap[idxb[p]*S_ + idxn[p]] = p;
  if (tid == 0) {
    float mm = fmaxf(fmaxf(redf[0], redf[1]), fmaxf(redf[2], redf[3]));
    l2invg[0] = -log2f(mm);
  }
}

// ---------------- K3: fused attention: softmax(QK^T/8) * scales @ V ----------------
// Best verified body (R20/R22: 116.8-117.1us total): 8-wave (512,1) blocks,
// IT_=8 (grid 640), deferred normalization (butterfly after PV), gaussian
// group-skip, VF n-plane layout (d=4c+n) -> 4 coalesced dwordx4 stores.
// SPILL CHECK each round: FETCH ~107MB / WRITE ~164MB, else it spilled.
__global__ __launch_bounds__(512, 1) void k3_attn(const float* __restrict__ Q,
                                                  const float* __restrict__ K,
                                                  const float* __restrict__ V,
                                                  const int* __restrict__ pmap,
                                                  const float* __restrict__ params,
                                                  const float* __restrict__ l2invg,
                                                  float* __restrict__ out) {
  __shared__ __bf16 KF[2][5][64][8];   // 10 KB   K[s=16n+c][d=32ks+8g+j]
  __shared__ __bf16 VF[3][4][64][8];   // 12 KB   V[s=32ks+8g+j][d=4c+n]  (n-plane layout)
  __shared__ __bf16 Wl[8][16][104];    // 26 KB   per-wave P tile; cols 80..95 zeroed
  __shared__ float4 pp[80];            // (yc, -isy*log2e, xc, -isx*log2e)
  __shared__ float  ppc[80];           // l2invg if active else 0
  __shared__ int    sact[5];           // any active s in group n?

  const int bh = blockIdx.y, b = bh / H_, bx = blockIdx.x;
  const int tid = threadIdx.x, lane = tid & 63, wid = tid >> 6;
  const int c = lane & 15, g = lane >> 4;

  if (tid < 5) sact[tid] = 0;

  // issue it=0 Q loads FIRST so they overlap staging + barrier
  const float* qb0 = Q + ((size_t)bh*L_ + bx*(128*IT_) + wid*16 + c)*D_ + g*8;
  float4 nqa0 = *(const float4*)(qb0);
  float4 nqa1 = *(const float4*)(qb0 + 4);
  float4 nqc0 = *(const float4*)(qb0 + 32);
  float4 nqc1 = *(const float4*)(qb0 + 36);

  // zero P pad cols 80..95 (read by PV ks=2 for g>=2, never written)
  *(uint2*)&Wl[wid][c][80 + g*4] = make_uint2(0u, 0u);

  // stage K fragments (RNE bf16)
  for (int e4 = tid; e4 < 80*16; e4 += 512) {
    int s = e4 >> 4, d = (e4 & 15) * 4;
    float4 kv = make_float4(0.f, 0.f, 0.f, 0.f);
    if (s < S_) kv = *(const float4*)&K[((size_t)bh*S_ + s)*D_ + d];
    int n = s >> 4, cc = s & 15, ks = d >> 5, gg = (d >> 3) & 3, jj = d & 7;
    uint2 pk;
    pk.x = (unsigned)bfb((__bf16)kv.x) | ((unsigned)bfb((__bf16)kv.y) << 16);
    pk.y = (unsigned)bfb((__bf16)kv.z) | ((unsigned)bfb((__bf16)kv.w) << 16);
    *(uint2*)&KF[ks][n][gg*16 + cc][jj] = pk;
  }
  // stage V fragments with d = 4c + n permutation: value at (s, d) goes to
  // n-plane (d&3), lane-col (d>>2). Enumerate s in [0,96) so ALL rows of
  // VF[ks=2] are written (round-3 NaN-poison bug).
  for (int e4 = tid; e4 < 96*16; e4 += 512) {
    int s = e4 >> 4, d = (e4 & 15) * 4;
    float4 vv = make_float4(0.f, 0.f, 0.f, 0.f);
    if (s < S_) vv = *(const float4*)&V[((size_t)bh*S_ + s)*D_ + d];
    int ks = s >> 5, gg = (s >> 3) & 3, jj = s & 7;
    int c0 = d >> 2;
    VF[ks][0][gg*16 + c0][jj] = (__bf16)vv.x;
    VF[ks][1][gg*16 + c0][jj] = (__bf16)vv.y;
    VF[ks][2][gg*16 + c0][jj] = (__bf16)vv.z;
    VF[ks][3][gg*16 + c0][jj] = (__bf16)vv.w;
  }
  __syncthreads();   // sact zeroing visible before pp loop sets it

  // per-s gaussian params
  for (int s = tid; s < 80; s += 512) {
    float4 v = make_float4(0.f, 0.f, 0.f, 0.f);
    float cs = 0.f;
    if (s < S_) {
      int pid = pmap[b*S_ + s];
      if (pid >= 0) {
        v.x = params[pid*8+1];            // yc
        v.y = -params[pid*8+3]*LOG2E;     // -isy*log2e
        v.z = params[pid*8+0];            // xc
        v.w = -params[pid*8+2]*LOG2E;     // -isx*log2e
        cs  = l2invg[0];
        sact[s >> 4] = 1;                 // benign race: all writers store 1
      }
    }
    pp[s] = v; ppc[s] = cs;
  }
  __syncthreads();

  int sa[5];
  #pragma unroll
  for (int n = 0; n < 5; ++n) sa[n] = sact[n];

  #pragma unroll 1
  for (int it = 0; it < IT_; ++it) {
    const int lt = bx*(128*IT_) + it*128 + wid*16;
    // consume prefetched Q; issue next tile's loads
    const float4 qa0 = nqa0, qa1 = nqa1, qc0 = nqc0, qc1 = nqc1;
    {
      const int itn = (it + 1 < IT_) ? it + 1 : it;
      const float* qn = qb0 + (size_t)itn * 128 * D_;
      nqa0 = *(const float4*)(qn);
      nqa1 = *(const float4*)(qn + 4);
      nqc0 = *(const float4*)(qn + 32);
      nqc1 = *(const float4*)(qn + 36);
    }
    bf16x8 qf[2];
    qf[0][0]=(__bf16)qa0.x; qf[0][1]=(__bf16)qa0.y; qf[0][2]=(__bf16)qa0.z; qf[0][3]=(__bf16)qa0.w;
    qf[0][4]=(__bf16)qa1.x; qf[0][5]=(__bf16)qa1.y; qf[0][6]=(__bf16)qa1.z; qf[0][7]=(__bf16)qa1.w;
    qf[1][0]=(__bf16)qc0.x; qf[1][1]=(__bf16)qc0.y; qf[1][2]=(__bf16)qc0.z; qf[1][3]=(__bf16)qc0.w;
    qf[1][4]=(__bf16)qc1.x; qf[1][5]=(__bf16)qc1.y; qf[1][6]=(__bf16)qc1.z; qf[1][7]=(__bf16)qc1.w;

    // QK^T: acc[n] covers s = 16n + c; rows l = lt + 4g + r
    f32x4 acc[5];
    #pragma unroll
    for (int n = 0; n < 5; ++n) acc[n] = f32x4{0.f, 0.f, 0.f, 0.f};
    #pragma unroll
    for (int ks = 0; ks < 2; ++ks)
      #pragma unroll
      for (int n = 0; n < 5; ++n)
        acc[n] = __builtin_amdgcn_mfma_f32_16x16x32_bf16(qf[ks], *(bf16x8*)&KF[ks][n][lane][0], acc[n], 0, 0, 0);
    // mask s >= 77, then exp2 WITHOUT max subtraction (shift-invariant, no ovf)
    if (c >= 13) {
      #pragma unroll
      for (int r = 0; r < 4; ++r) acc[4][r] = -1e30f;
    }
    #pragma unroll
    for (int n = 0; n < 5; ++n)
      #pragma unroll
      for (int r = 0; r < 4; ++r) acc[n][r] = __builtin_amdgcn_exp2f(acc[n][r] * SC_L2);
    // lane-local partial row-sums only -- butterfly deferred past PV
    float ssum[4];
    #pragma unroll
    for (int r = 0; r < 4; ++r)
      ssum[r] = acc[0][r] + acc[1][r] + acc[2][r] + acc[3][r] + acc[4][r];
    // gaussian scales (group-skipped) + write UNNORMALIZED P tile
    // X = l>>6 and Y-base = l&63 are wave-constant: lt % 64 in {0,16,32,48}
    const float Xf = (float)(lt >> 6);
    const float Yb = (float)((lt & 63) + g*4);
    #pragma unroll
    for (int n = 0; n < 5; ++n) {
      if (sa[n]) {
        const float4 sp4 = pp[16*n + c];
        const float tx = Xf - sp4.z;
        const float Cn = fmaf(tx*tx, sp4.w, ppc[16*n + c]);
        #pragma unroll
        for (int r = 0; r < 4; ++r) {
          float t = (Yb + (float)r) - sp4.x;
          float gm = __builtin_amdgcn_exp2f(fmaf(t*t, sp4.y, Cn));
          Wl[wid][g*4 + r][16*n + c] = (__bf16)(acc[n][r] * gm);
        }
      } else {
        #pragma unroll
        for (int r = 0; r < 4; ++r)
          Wl[wid][g*4 + r][16*n + c] = (__bf16)acc[n][r];
      }
    }
    // PV (only Wl comes from LDS on the spine; butterfly overlaps).
    // Output col of call n = 4c + n (VF n-plane layout).
    f32x4 pacc[4];
    #pragma unroll
    for (int n = 0; n < 4; ++n) pacc[n] = f32x4{0.f, 0.f, 0.f, 0.f};
    #pragma unroll
    for (int ks = 0; ks < 3; ++ks) {
      bf16x8 wf = *(bf16x8*)&Wl[wid][c][ks*32 + g*8];
      #pragma unroll
      for (int n = 0; n < 4; ++n) {
        bf16x8 vf = *(bf16x8*)&VF[ks][n][lane][0];
        pacc[n] = __builtin_amdgcn_mfma_f32_16x16x32_bf16(wf, vf, pacc[n], 0, 0, 0);
      }
    }
    // row-sum butterfly + normalize (post-PV; rows of pacc == rows of ssum)
    float sm[4];
    #pragma unroll
    for (int r = 0; r < 4; ++r) {
      float s0 = ssum[r];
      #pragma unroll
      for (int s = 1; s < 16; s <<= 1) s0 += __shfl_xor(s0, s, 64);
      sm[r] = __builtin_amdgcn_rcpf(s0);
    }
    // store: per row r one float4 at cols 4c..4c+3 -- 4 dwordx4, each instr
    // covering 4 rows x 256B contiguous
    float* ob = out + ((size_t)bh*L_ + lt + g*4)*D_ + c*4;
    #pragma unroll
    for (int r = 0; r < 4; ++r) {
      float4 o;
      o.x = pacc[0][r] * sm[r];
      o.y = pacc[1][r] * sm[r];
      o.z = pacc[2][r] * sm[r];
      o.w = pacc[3][r] * sm[r];
      *(float4*)&ob[(size_t)r*D_] = o;
    }
  }
}

extern "C" void kernel_launch(void* const* d_in, const int* in_sizes, int n_in,
                              void* d_out, int out_size, void* d_ws, size_t ws_size,
                              hipStream_t stream) {
  const float* Q  = (const float*)d_in[0];
  const float* Kp = (const float*)d_in[1];
  const float* Vp = (const float*)d_in[2];
  const int* idxb = (const int*)d_in[3];
  const int* idxn = (const int*)d_in[4];
  float* out = (float*)d_out;

  char* w = (char*)d_ws;
  float* moments = (float*)w;               // NP*8 floats (atomic accumulators)
  int*   counter = (int*)(moments + NP_*8); // 1 int (+pad to 16B)
  float* params  = (float*)(counter + 4);   // NP*8 floats
  float* l2invg  = params + NP_*8;          // 1 float (+pad)
  int*   pmap    = (int*)(l2invg + 4);      // B*S ints

  // zero moments + counter (one memset, graph-safe)
  hipMemsetAsync(w, 0, (size_t)NP_*8*sizeof(float) + 16, stream);
  k1_subj<<<dim3(L_/128, B_), 256, 0, stream>>>(Q, Kp, idxb, idxn,
                                                moments, counter, params, pmap, l2invg);
  k3_attn<<<dim3(L_/(128*IT_), B_*H_), 512, 0, stream>>>(Q, Kp, Vp, pmap, params, l2invg, out);
}

// Round 24
// 116.748 us; speedup vs baseline: 1.4964x; 1.4964x over previous
//
#include <hip/hip_runtime.h>
#include <math.h>

#define B_ 16
#define H_ 10
#define L_ 4096
#define S_ 77
#define D_ 64
#define NE_ 20
#define NP_ (B_*NE_)
#define SHRINK_ 2.0f
#define LOG2E 1.4426950408889634f
#define SC_L2 (0.125f*LOG2E)
#define IT_ 8   // k3 l-tiles per block; 8 waves x 16 rows x IT_ = 1024 rows/block -> grid 640

typedef __bf16 bf16x8 __attribute__((ext_vector_type(8)));
typedef float  f32x4  __attribute__((ext_vector_type(4)));

static __device__ __forceinline__ unsigned short bfb(__bf16 x) {
  return __builtin_bit_cast(unsigned short, x);
}
static __device__ __forceinline__ __bf16 mkbf(unsigned short x) {
  return __builtin_bit_cast(__bf16, x);
}

// ---------------- K1: subj scores via MFMA + FUSED moment accumulation ----------------
// Within a 64-l tile y=l>>6 is CONSTANT (Y0): only 3 sums per pair needed
// (S0, S1=sum e*x, S2=sum e*x^2); y-moments are Y0*S0 / Y0^2*S0. Parallel
// reduce: 8 threads/pair, 3-step shfl_xor, leaders accumulate in regs,
// 100 atomics per block at the end. (moments buffer zeroed by memset.)
// R21 partials variant regressed (+3.6us); R23 last-block-finish with
// __threadfence regressed catastrophically (+58us: 2048 device-scope
// fences = cross-XCD L2 flush per wave). Keep memset + atomics + k2b.
__global__ __launch_bounds__(256, 3) void k1_subj(const float* __restrict__ Q,
                                                  const float* __restrict__ K,
                                                  const int* __restrict__ idxb,
                                                  const int* __restrict__ idxn,
                                                  float* __restrict__ moments) {
  __shared__ __bf16 KF[20][2][64][8];   // 40 KB
  __shared__ float T[NE_][66];          // transpose tile (pair x 64 l)
  __shared__ int bs[NE_], ss[NE_], s_uni;
  const int i = blockIdx.y, bx = blockIdx.x;
  const int tid = threadIdx.x, lane = tid & 63, wid = tid >> 6;
  const int c = lane & 15, g = lane >> 4;
  if (tid < NE_) { bs[tid] = idxb[i*NE_ + tid]; ss[tid] = idxn[i*NE_ + tid]; }
  __syncthreads();
  if (tid == 0) { int u = 1; for (int j = 1; j < NE_; ++j) u &= (bs[j] == bs[0]); s_uni = u; }
  for (int e4 = tid; e4 < 32*160; e4 += 256) {
    int j = e4 / 160, k = (e4 - j*160) * 4;
    float4 kv = make_float4(0.f, 0.f, 0.f, 0.f);
    if (j < NE_) kv = *(const float4*)&K[(((size_t)bs[j]*H_ + (k >> 6))*S_ + ss[j])*D_ + (k & 63)];
    int ks = k >> 5, gg = (k >> 3) & 3, jj = k & 7, n = j >> 4, cc = j & 15;
    uint2 pk;
    pk.x = (unsigned)bfb((__bf16)kv.x) | ((unsigned)bfb((__bf16)kv.y) << 16);
    pk.y = (unsigned)bfb((__bf16)kv.z) | ((unsigned)bfb((__bf16)kv.w) << 16);
    *(uint2*)&KF[ks][n][gg*16 + cc][jj] = pk;
  }
  __syncthreads();
  if (!s_uni) {
    // generic fallback (idx_b varies within a row): correctness-only
    int ll = tid & 63;
    for (int ii = 0; ii < 2; ++ii) {
      int l = bx*128 + ii*64 + ll;
      for (int j = tid >> 6; j < NE_; j += 4) {
        float a = 0.f;
        for (int h = 0; h < H_; ++h) {
          const float* qp = Q + (((size_t)bs[j]*H_ + h)*L_ + l)*D_;
          const float* kp = K + (((size_t)bs[j]*H_ + h)*S_ + ss[j])*D_;
          for (int d = 0; d < 64; ++d) a += qp[d]*kp[d];
        }
        float e = __builtin_amdgcn_exp2f(a * (1.0f/80.0f) * LOG2E);
        float y = (float)(l >> 6), x = (float)(l & 63);
        atomicAdd(&moments[(i*NE_ + j)*8 + 0], e);
        atomicAdd(&moments[(i*NE_ + j)*8 + 1], e*y);
        atomicAdd(&moments[(i*NE_ + j)*8 + 2], e*x);
        atomicAdd(&moments[(i*NE_ + j)*8 + 3], e*y*y);
        atomicAdd(&moments[(i*NE_ + j)*8 + 4], e*x*x);
      }
    }
    return;
  }
  const int b0 = bs[0];
  const int rj = tid >> 3;          // pair handled in reduce (active if < 20)
  const int rl = (tid & 7) * 8;     // 8-element slice
  float m0 = 0.f, m1 = 0.f, m2 = 0.f, m3 = 0.f, m4 = 0.f;
  #pragma unroll 1
  for (int it = 0; it < 2; ++it) {
    const int lrow = bx*128 + it*64 + wid*16 + c;
    f32x4 acc0 = {0.f,0.f,0.f,0.f}, acc1 = {0.f,0.f,0.f,0.f};
    #pragma unroll 4
    for (int ks = 0; ks < 20; ++ks) {
      const float* qp = Q + (((size_t)b0*H_ + (ks >> 1))*L_ + lrow)*D_ + (ks & 1)*32 + g*8;
      const float4 a = *(const float4*)qp;
      const float4 bq = *(const float4*)(qp + 4);
      bf16x8 af;
      af[0]=(__bf16)a.x;  af[1]=(__bf16)a.y;  af[2]=(__bf16)a.z;  af[3]=(__bf16)a.w;
      af[4]=(__bf16)bq.x; af[5]=(__bf16)bq.y; af[6]=(__bf16)bq.z; af[7]=(__bf16)bq.w;
      bf16x8 k0 = *(bf16x8*)&KF[ks][0][lane][0];
      bf16x8 k1 = *(bf16x8*)&KF[ks][1][lane][0];
      acc0 = __builtin_amdgcn_mfma_f32_16x16x32_bf16(af, k0, acc0, 0, 0, 0);
      acc1 = __builtin_amdgcn_mfma_f32_16x16x32_bf16(af, k1, acc1, 0, 0, 0);
    }
    const float sc = 1.0f/80.0f;
    #pragma unroll
    for (int r = 0; r < 4; ++r) {
      int ll = wid*16 + g*4 + r;
      T[c][ll] = acc0[r]*sc;
      if (c < 4) T[16 + c][ll] = acc1[r]*sc;
    }
    __syncthreads();
    // parallel moment reduce of this 64-l tile; y = Y0 constant over tile
    if (rj < NE_) {
      float s0 = 0.f, s1 = 0.f, s2 = 0.f;
      #pragma unroll
      for (int u = 0; u < 8; ++u) {
        float e = __builtin_amdgcn_exp2f(T[rj][rl + u] * LOG2E);
        float x = (float)(rl + u);
        s0 += e; s1 += e*x; s2 += e*x*x;
      }
      #pragma unroll
      for (int s = 1; s < 8; s <<= 1) {
        s0 += __shfl_xor(s0, s, 64);
        s1 += __shfl_xor(s1, s, 64);
        s2 += __shfl_xor(s2, s, 64);
      }
      if ((tid & 7) == 0) {
        const float Y0 = (float)(bx*2 + it);
        m0 += s0; m1 += Y0*s0; m2 += s1; m3 += Y0*Y0*s0; m4 += s2;
      }
    }
    __syncthreads();
  }
  if (rj < NE_ && (tid & 7) == 0) {
    float* mp = &moments[(size_t)(i*NE_ + rj)*8];
    atomicAdd(mp + 0, m0);
    atomicAdd(mp + 1, m1);
    atomicAdd(mp + 2, m2);
    atomicAdd(mp + 3, m3);
    atomicAdd(mp + 4, m4);
  }
}

// ---------------- K2b: params from moments + global grid max + (b,s)->pair map ----
__global__ __launch_bounds__(256) void k2b_finish(const float* __restrict__ moments,
                                                  const int* __restrict__ idxb,
                                                  const int* __restrict__ idxn,
                                                  float* __restrict__ params,
                                                  int* __restrict__ pmap,
                                                  float* __restrict__ l2invg) {
  const int tid = threadIdx.x;
  for (int p = tid; p < NP_; p += 256) {
    float m0 = moments[p*8+0], m1 = moments[p*8+1], m2 = moments[p*8+2];
    float m3 = moments[p*8+3], m4 = moments[p*8+4];
    float xc = m2/m0, yc = m1/m0;
    float varx = m4/m0 - xc*xc;
    float vary = m3/m0 - yc*yc;
    float sh = SHRINK_ - 1.0f;
    float isx = sh*sh/(2.f*varx), isy = sh*sh/(2.f*vary);
    float rx = rintf(xc), ry = rintf(yc);
    float mv = __expf(-((rx-xc)*(rx-xc)*isx + (ry-yc)*(ry-yc)*isy));
    params[p*8+0] = xc; params[p*8+1] = yc;
    params[p*8+2] = isx; params[p*8+3] = isy; params[p*8+4] = mv;
  }
  for (int e = tid; e < B_*S_; e += 256) pmap[e] = -1;
  __syncthreads();
  for (int p = tid; p < NP_; p += 256) pmap[idxb[p]*S_ + idxn[p]] = p;
  float m = 0.f;
  for (int p = tid; p < NP_; p += 256) m = fmaxf(m, params[p*8+4]);
  #pragma unroll
  for (int s = 1; s < 64; s <<= 1) m = fmaxf(m, __shfl_xor(m, s, 64));
  __shared__ float red[4];
  if ((tid & 63) == 0) red[tid >> 6] = m;
  __syncthreads();
  if (tid == 0) {
    m = fmaxf(fmaxf(red[0], red[1]), fmaxf(red[2], red[3]));
    l2invg[0] = -log2f(m);
  }
}

// ---------------- K3: fused attention: softmax(QK^T/8) * scales @ V ----------------
// CONVERGED configuration (R20/R22: 116.8-117.1us total): 8-wave (512,1)
// blocks, IT_=8 (grid 640), deferred normalization (butterfly after PV),
// gaussian group-skip, VF n-plane layout (d=4c+n) -> 4 coalesced dwordx4
// stores. SPILL CHECK: FETCH ~107MB / WRITE ~164MB.
__global__ __launch_bounds__(512, 1) void k3_attn(const float* __restrict__ Q,
                                                  const float* __restrict__ K,
                                                  const float* __restrict__ V,
                                                  const int* __restrict__ pmap,
                                                  const float* __restrict__ params,
                                                  const float* __restrict__ l2invg,
                                                  float* __restrict__ out) {
  __shared__ __bf16 KF[2][5][64][8];   // 10 KB   K[s=16n+c][d=32ks+8g+j]
  __shared__ __bf16 VF[3][4][64][8];   // 12 KB   V[s=32ks+8g+j][d=4c+n]  (n-plane layout)
  __shared__ __bf16 Wl[8][16][104];    // 26 KB   per-wave P tile; cols 80..95 zeroed
  __shared__ float4 pp[80];            // (yc, -isy*log2e, xc, -isx*log2e)
  __shared__ float  ppc[80];           // l2invg if active else 0
  __shared__ int    sact[5];           // any active s in group n?

  const int bh = blockIdx.y, b = bh / H_, bx = blockIdx.x;
  const int tid = threadIdx.x, lane = tid & 63, wid = tid >> 6;
  const int c = lane & 15, g = lane >> 4;

  if (tid < 5) sact[tid] = 0;

  // issue it=0 Q loads FIRST so they overlap staging + barrier
  const float* qb0 = Q + ((size_t)bh*L_ + bx*(128*IT_) + wid*16 + c)*D_ + g*8;
  float4 nqa0 = *(const float4*)(qb0);
  float4 nqa1 = *(const float4*)(qb0 + 4);
  float4 nqc0 = *(const float4*)(qb0 + 32);
  float4 nqc1 = *(const float4*)(qb0 + 36);

  // zero P pad cols 80..95 (read by PV ks=2 for g>=2, never written)
  *(uint2*)&Wl[wid][c][80 + g*4] = make_uint2(0u, 0u);

  // stage K fragments (RNE bf16)
  for (int e4 = tid; e4 < 80*16; e4 += 512) {
    int s = e4 >> 4, d = (e4 & 15) * 4;
    float4 kv = make_float4(0.f, 0.f, 0.f, 0.f);
    if (s < S_) kv = *(const float4*)&K[((size_t)bh*S_ + s)*D_ + d];
    int n = s >> 4, cc = s & 15, ks = d >> 5, gg = (d >> 3) & 3, jj = d & 7;
    uint2 pk;
    pk.x = (unsigned)bfb((__bf16)kv.x) | ((unsigned)bfb((__bf16)kv.y) << 16);
    pk.y = (unsigned)bfb((__bf16)kv.z) | ((unsigned)bfb((__bf16)kv.w) << 16);
    *(uint2*)&KF[ks][n][gg*16 + cc][jj] = pk;
  }
  // stage V fragments with d = 4c + n permutation: value at (s, d) goes to
  // n-plane (d&3), lane-col (d>>2). Enumerate s in [0,96) so ALL rows of
  // VF[ks=2] are written (round-3 NaN-poison bug).
  for (int e4 = tid; e4 < 96*16; e4 += 512) {
    int s = e4 >> 4, d = (e4 & 15) * 4;
    float4 vv = make_float4(0.f, 0.f, 0.f, 0.f);
    if (s < S_) vv = *(const float4*)&V[((size_t)bh*S_ + s)*D_ + d];
    int ks = s >> 5, gg = (s >> 3) & 3, jj = s & 7;
    int c0 = d >> 2;
    VF[ks][0][gg*16 + c0][jj] = (__bf16)vv.x;
    VF[ks][1][gg*16 + c0][jj] = (__bf16)vv.y;
    VF[ks][2][gg*16 + c0][jj] = (__bf16)vv.z;
    VF[ks][3][gg*16 + c0][jj] = (__bf16)vv.w;
  }
  __syncthreads();   // sact zeroing visible before pp loop sets it

  // per-s gaussian params
  for (int s = tid; s < 80; s += 512) {
    float4 v = make_float4(0.f, 0.f, 0.f, 0.f);
    float cs = 0.f;
    if (s < S_) {
      int pid = pmap[b*S_ + s];
      if (pid >= 0) {
        v.x = params[pid*8+1];            // yc
        v.y = -params[pid*8+3]*LOG2E;     // -isy*log2e
        v.z = params[pid*8+0];            // xc
        v.w = -params[pid*8+2]*LOG2E;     // -isx*log2e
        cs  = l2invg[0];
        sact[s >> 4] = 1;                 // benign race: all writers store 1
      }
    }
    pp[s] = v; ppc[s] = cs;
  }
  __syncthreads();

  int sa[5];
  #pragma unroll
  for (int n = 0; n < 5; ++n) sa[n] = sact[n];

  #pragma unroll 1
  for (int it = 0; it < IT_; ++it) {
    const int lt = bx*(128*IT_) + it*128 + wid*16;
    // consume prefetched Q; issue next tile's loads
    const float4 qa0 = nqa0, qa1 = nqa1, qc0 = nqc0, qc1 = nqc1;
    {
      const int itn = (it + 1 < IT_) ? it + 1 : it;
      const float* qn = qb0 + (size_t)itn * 128 * D_;
      nqa0 = *(const float4*)(qn);
      nqa1 = *(const float4*)(qn + 4);
      nqc0 = *(const float4*)(qn + 32);
      nqc1 = *(const float4*)(qn + 36);
    }
    bf16x8 qf[2];
    qf[0][0]=(__bf16)qa0.x; qf[0][1]=(__bf16)qa0.y; qf[0][2]=(__bf16)qa0.z; qf[0][3]=(__bf16)qa0.w;
    qf[0][4]=(__bf16)qa1.x; qf[0][5]=(__bf16)qa1.y; qf[0][6]=(__bf16)qa1.z; qf[0][7]=(__bf16)qa1.w;
    qf[1][0]=(__bf16)qc0.x; qf[1][1]=(__bf16)qc0.y; qf[1][2]=(__bf16)qc0.z; qf[1][3]=(__bf16)qc0.w;
    qf[1][4]=(__bf16)qc1.x; qf[1][5]=(__bf16)qc1.y; qf[1][6]=(__bf16)qc1.z; qf[1][7]=(__bf16)qc1.w;

    // QK^T: acc[n] covers s = 16n + c; rows l = lt + 4g + r
    f32x4 acc[5];
    #pragma unroll
    for (int n = 0; n < 5; ++n) acc[n] = f32x4{0.f, 0.f, 0.f, 0.f};
    #pragma unroll
    for (int ks = 0; ks < 2; ++ks)
      #pragma unroll
      for (int n = 0; n < 5; ++n)
        acc[n] = __builtin_amdgcn_mfma_f32_16x16x32_bf16(qf[ks], *(bf16x8*)&KF[ks][n][lane][0], acc[n], 0, 0, 0);
    // mask s >= 77, then exp2 WITHOUT max subtraction (shift-invariant, no ovf)
    if (c >= 13) {
      #pragma unroll
      for (int r = 0; r < 4; ++r) acc[4][r] = -1e30f;
    }
    #pragma unroll
    for (int n = 0; n < 5; ++n)
      #pragma unroll
      for (int r = 0; r < 4; ++r) acc[n][r] = __builtin_amdgcn_exp2f(acc[n][r] * SC_L2);
    // lane-local partial row-sums only -- butterfly deferred past PV
    float ssum[4];
    #pragma unroll
    for (int r = 0; r < 4; ++r)
      ssum[r] = acc[0][r] + acc[1][r] + acc[2][r] + acc[3][r] + acc[4][r];
    // gaussian scales (group-skipped) + write UNNORMALIZED P tile
    // X = l>>6 and Y-base = l&63 are wave-constant: lt % 64 in {0,16,32,48}
    const float Xf = (float)(lt >> 6);
    const float Yb = (float)((lt & 63) + g*4);
    #pragma unroll
    for (int n = 0; n < 5; ++n) {
      if (sa[n]) {
        const float4 sp4 = pp[16*n + c];
        const float tx = Xf - sp4.z;
        const float Cn = fmaf(tx*tx, sp4.w, ppc[16*n + c]);
        #pragma unroll
        for (int r = 0; r < 4; ++r) {
          float t = (Yb + (float)r) - sp4.x;
          float gm = __builtin_amdgcn_exp2f(fmaf(t*t, sp4.y, Cn));
          Wl[wid][g*4 + r][16*n + c] = (__bf16)(acc[n][r] * gm);
        }
      } else {
        #pragma unroll
        for (int r = 0; r < 4; ++r)
          Wl[wid][g*4 + r][16*n + c] = (__bf16)acc[n][r];
      }
    }
    // PV (only Wl comes from LDS on the spine; butterfly overlaps).
    // Output col of call n = 4c + n (VF n-plane layout).
    f32x4 pacc[4];
    #pragma unroll
    for (int n = 0; n < 4; ++n) pacc[n] = f32x4{0.f, 0.f, 0.f, 0.f};
    #pragma unroll
    for (int ks = 0; ks < 3; ++ks) {
      bf16x8 wf = *(bf16x8*)&Wl[wid][c][ks*32 + g*8];
      #pragma unroll
      for (int n = 0; n < 4; ++n) {
        bf16x8 vf = *(bf16x8*)&VF[ks][n][lane][0];
        pacc[n] = __builtin_amdgcn_mfma_f32_16x16x32_bf16(wf, vf, pacc[n], 0, 0, 0);
      }
    }
    // row-sum butterfly + normalize (post-PV; rows of pacc == rows of ssum)
    float sm[4];
    #pragma unroll
    for (int r = 0; r < 4; ++r) {
      float s0 = ssum[r];
      #pragma unroll
      for (int s = 1; s < 16; s <<= 1) s0 += __shfl_xor(s0, s, 64);
      sm[r] = __builtin_amdgcn_rcpf(s0);
    }
    // store: per row r one float4 at cols 4c..4c+3 -- 4 dwordx4, each instr
    // covering 4 rows x 256B contiguous
    float* ob = out + ((size_t)bh*L_ + lt + g*4)*D_ + c*4;
    #pragma unroll
    for (int r = 0; r < 4; ++r) {
      float4 o;
      o.x = pacc[0][r] * sm[r];
      o.y = pacc[1][r] * sm[r];
      o.z = pacc[2][r] * sm[r];
      o.w = pacc[3][r] * sm[r];
      *(float4*)&ob[(size_t)r*D_] = o;
    }
  }
}

extern "C" void kernel_launch(void* const* d_in, const int* in_sizes, int n_in,
                              void* d_out, int out_size, void* d_ws, size_t ws_size,
                              hipStream_t stream) {
  const float* Q  = (const float*)d_in[0];
  const float* Kp = (const float*)d_in[1];
  const float* Vp = (const float*)d_in[2];
  const int* idxb = (const int*)d_in[3];
  const int* idxn = (const int*)d_in[4];
  float* out = (float*)d_out;

  char* w = (char*)d_ws;
  float* params  = (float*)w;               // NP*8 floats
  float* l2invg  = params + NP_*8;          // 1 float (+pad)
  int*   pmap    = (int*)(l2invg + 4);      // B*S ints
  float* moments = (float*)(pmap + B_*S_);  // NP*8 floats (atomic accumulators)

  hipMemsetAsync(moments, 0, (size_t)NP_*8*sizeof(float), stream);
  k1_subj<<<dim3(L_/128, B_), 256, 0, stream>>>(Q, Kp, idxb, idxn, moments);
  k2b_finish<<<1, 256, 0, stream>>>(moments, idxb, idxn, params, pmap, l2invg);
  k3_attn<<<dim3(L_/(128*IT_), B_*H_), 512, 0, stream>>>(Q, Kp, Vp, pmap, params, l2invg, out);
}